// Round 1
// baseline (29.600 us; speedup 1.0000x reference)
//
#include <hip/hip_runtime.h>
#include <hip/hip_bf16.h>

#define IN_FEATURES  8192
#define OUT_FEATURES 512
#define SF           16      // IN_FEATURES / OUT_FEATURES
#define BATCH        4096

// out[b, o] = bias[o] + sum_{k=0..15} x[b, o*16+k] * w[o, o*16+k]
__global__ __launch_bounds__(256) void banded_linear_kernel(
    const float* __restrict__ x,     // [BATCH, IN_FEATURES]
    const float* __restrict__ w,     // [OUT_FEATURES, IN_FEATURES]
    const float* __restrict__ bias,  // [OUT_FEATURES]
    float* __restrict__ out)         // [BATCH, OUT_FEATURES]
{
    const int tid = blockIdx.x * blockDim.x + threadIdx.x;   // b*512 + o
    const int o = tid & (OUT_FEATURES - 1);
    const int b = tid >> 9;  // /512

    // x offset: b*8192 + o*16  (multiple of 16 floats -> 64B aligned)
    const float4* __restrict__ xp =
        reinterpret_cast<const float4*>(x + ((size_t)b << 13) + ((size_t)o << 4));
    // w offset: o*8192 + o*16 = o*8208 (multiple of 16 floats -> 64B aligned)
    const float4* __restrict__ wp =
        reinterpret_cast<const float4*>(w + (size_t)o * (IN_FEATURES + SF));

    float acc = 0.0f;
#pragma unroll
    for (int k = 0; k < 4; ++k) {
        const float4 xv = xp[k];
        const float4 wv = wp[k];
        acc = fmaf(xv.x, wv.x, acc);
        acc = fmaf(xv.y, wv.y, acc);
        acc = fmaf(xv.z, wv.z, acc);
        acc = fmaf(xv.w, wv.w, acc);
    }
    out[tid] = acc + bias[o];
}

extern "C" void kernel_launch(void* const* d_in, const int* in_sizes, int n_in,
                              void* d_out, int out_size, void* d_ws, size_t ws_size,
                              hipStream_t stream) {
    const float* x    = (const float*)d_in[0];
    const float* w    = (const float*)d_in[1];
    const float* bias = (const float*)d_in[2];
    float* out = (float*)d_out;

    const int total = BATCH * OUT_FEATURES;        // 2,097,152
    const int block = 256;
    const int grid  = total / block;               // 8192
    banded_linear_kernel<<<grid, block, 0, stream>>>(x, w, bias, out);
}

// Round 2
// 25.356 us; speedup vs baseline: 1.1674x; 1.1674x over previous
//
#include <hip/hip_runtime.h>
#include <hip/hip_bf16.h>

#define IN_FEATURES  8192
#define OUT_FEATURES 512
#define SF           16      // IN_FEATURES / OUT_FEATURES
#define BATCH        4096
#define B_ITERS      16      // batches per thread

// out[b, o] = bias[o] + sum_{k=0..15} x[b, o*16+k] * w[o, o*16+k]
//
// 4 lanes per output element: lane j (0..3) handles x[b, o*16 + 4j .. +3].
// Wave-level x access: 64 lanes read 64 consecutive float4s = 1024 B
// contiguous -> one fully-coalesced transaction per load instruction.
// Cross-lane reduce over the 4-lane quad via 2x shfl_xor (DPP).
__global__ __launch_bounds__(256) void banded_linear_kernel(
    const float* __restrict__ x,     // [BATCH, IN_FEATURES]
    const float* __restrict__ w,     // [OUT_FEATURES, IN_FEATURES]
    const float* __restrict__ bias,  // [OUT_FEATURES]
    float* __restrict__ out)         // [BATCH, OUT_FEATURES]
{
    const int gid  = blockIdx.x * blockDim.x + threadIdx.x; // [0, 524288)
    const int j    = gid & 3;          // quarter of the 16-wide band
    const int o    = (gid >> 2) & (OUT_FEATURES - 1);
    const int slab = gid >> 11;        // [0, 256): owns 16 consecutive batches

    // weight quarter for this (o, j): row offset o*8208 floats + j*4
    const float4 wv = *reinterpret_cast<const float4*>(
        w + (size_t)o * (IN_FEATURES + SF) + (j << 2));
    const float bv = bias[o];

    const float* xbase = x + ((size_t)slab * B_ITERS << 13) + ((size_t)o << 4) + (j << 2);
    float* obase = out + ((size_t)slab * B_ITERS << 9) + o;

#pragma unroll 4
    for (int i = 0; i < B_ITERS; ++i) {
        const float4 xv = *reinterpret_cast<const float4*>(xbase + ((size_t)i << 13));
        float acc = fmaf(xv.x, wv.x,
                    fmaf(xv.y, wv.y,
                    fmaf(xv.z, wv.z, xv.w * wv.w)));
        // reduce across the 4-lane quad
        acc += __shfl_xor(acc, 1, 64);
        acc += __shfl_xor(acc, 2, 64);
        if (j == 0) {
            obase[(size_t)i << 9] = acc + bv;
        }
    }
}

extern "C" void kernel_launch(void* const* d_in, const int* in_sizes, int n_in,
                              void* d_out, int out_size, void* d_ws, size_t ws_size,
                              hipStream_t stream) {
    const float* x    = (const float*)d_in[0];
    const float* w    = (const float*)d_in[1];
    const float* bias = (const float*)d_in[2];
    float* out = (float*)d_out;

    // total threads = BATCH/B_ITERS * OUT_FEATURES * 4 = 256 * 512 * 4 = 524288
    const int block = 256;
    const int grid  = (BATCH / B_ITERS) * OUT_FEATURES * 4 / block;  // 2048
    banded_linear_kernel<<<grid, block, 0, stream>>>(x, w, bias, out);
}